// Round 1
// baseline (2749.455 us; speedup 1.0000x reference)
//
#include <hip/hip_runtime.h>
#include <math.h>

#define B_    32
#define T_    128
#define D_    512
#define FF_   2048
#define E_    8
#define NL_   3
#define NF_   16
#define FEAT_ 200
#define BT_   4096   // B*T

// ---------------------------------------------------------------------------
// Generic 64x64-tile SGEMM, 256 threads, 4x4 micro-tile, BK=16.
// MODE 0: C[z] = A[z] @ B[z] + bias[z]   (z batch via strides; rows direct)
// MODE 1: MoE GEMM1: A rows gathered via tok_list[z*BT+m], m < counts[z];
//         C rows stored at offsets[z]+m; epilogue ReLU(acc + bias[z][n])
// MODE 2: MoE GEMM2: A rows at offsets[z]+m; C rows at offsets[z]+m;
//         epilogue acc + bias[z][n]
// ---------------------------------------------------------------------------
template <int MODE>
__global__ __launch_bounds__(256)
void gemm_k(const float* __restrict__ A, const float* __restrict__ Bm,
            const float* __restrict__ bias, float* __restrict__ C,
            int K, int lda, int ldb, int ldc,
            long strA, long strB, long strC, int strBias,
            const int* __restrict__ counts, const int* __restrict__ offsets,
            const int* __restrict__ tok_list)
{
    const int z  = blockIdx.z;
    const int m0 = blockIdx.y * 64, n0 = blockIdx.x * 64;
    int rows = 0, rowoff = 0;
    if constexpr (MODE != 0) {
        rows = counts[z];
        if (m0 >= rows) return;
        rowoff = offsets[z];
    }
    const float* Ab    = A    + (long)z * strA;
    const float* Bb    = Bm   + (long)z * strB;
    const float* biasb = bias + (long)z * strBias;
    float*       Cb    = C    + (long)z * strC;

    __shared__ float As[16][68];   // As[k][m], padded to kill write conflicts
    __shared__ float Bs[16][64];   // Bs[k][n]

    const int tid = threadIdx.x;
    const int tx  = tid & 15, ty = tid >> 4;

    // A-load mapping: thread loads A[m0 + tid/4][k0 + (tid%4)*4 .. +3]
    const int ar  = tid >> 2;
    const int akc = (tid & 3) * 4;
    long arow;
    if constexpr (MODE == 1) {
        int mr = m0 + ar;
        int mg = (mr < rows) ? mr : (rows - 1);
        arow = tok_list[z * BT_ + mg];
    } else if constexpr (MODE == 2) {
        int mr = m0 + ar;
        int mg = (mr < rows) ? mr : (rows - 1);
        arow = rowoff + mg;
    } else {
        arow = m0 + ar;
    }
    const float* Arow = Ab + arow * (long)lda;

    // B-load mapping: thread loads B[k0 + tid/16][n0 + (tid%16)*4 .. +3]
    const int bkr = tid >> 4;
    const int bnc = (tid & 15) * 4;

    float acc[4][4];
#pragma unroll
    for (int i = 0; i < 4; ++i)
#pragma unroll
        for (int j = 0; j < 4; ++j) acc[i][j] = 0.f;

    for (int k0 = 0; k0 < K; k0 += 16) {
        // ---- stage A tile ----
        if (k0 + 16 <= K) {
            float4 a = *(const float4*)(Arow + k0 + akc);
            As[akc + 0][ar] = a.x; As[akc + 1][ar] = a.y;
            As[akc + 2][ar] = a.z; As[akc + 3][ar] = a.w;
        } else {
#pragma unroll
            for (int j = 0; j < 4; ++j) {
                int kk = k0 + akc + j;
                As[akc + j][ar] = (kk < K) ? Arow[kk] : 0.f;
            }
        }
        // ---- stage B tile ----
        {
            int kk = k0 + bkr;
            float4 b;
            if (kk < K) b = *(const float4*)(Bb + (long)kk * ldb + n0 + bnc);
            else        b = make_float4(0.f, 0.f, 0.f, 0.f);
            *(float4*)&Bs[bkr][bnc] = b;
        }
        __syncthreads();
#pragma unroll
        for (int k = 0; k < 16; ++k) {
            float4 av = *(const float4*)&As[k][ty * 4];
            float4 bv = *(const float4*)&Bs[k][tx * 4];
            float am[4] = {av.x, av.y, av.z, av.w};
            float bn[4] = {bv.x, bv.y, bv.z, bv.w};
#pragma unroll
            for (int i = 0; i < 4; ++i)
#pragma unroll
                for (int j = 0; j < 4; ++j)
                    acc[i][j] = fmaf(am[i], bn[j], acc[i][j]);
        }
        __syncthreads();
    }

    // ---- epilogue ----
#pragma unroll
    for (int i = 0; i < 4; ++i) {
        int m = m0 + ty * 4 + i;
        if (MODE != 0 && m >= rows) continue;
        long crow = (MODE != 0) ? (long)(rowoff + m) : (long)m;
        float*       Cp = Cb + crow * (long)ldc + n0 + tx * 4;
        const float* bp = biasb + n0 + tx * 4;
#pragma unroll
        for (int j = 0; j < 4; ++j) {
            float v = acc[i][j] + bp[j];
            if constexpr (MODE == 1) v = fmaxf(v, 0.f);
            Cp[j] = v;
        }
    }
}

// ---------------------------------------------------------------------------
// emb[t] = embed_table[src[t]]   (gather 200 floats per token)
// ---------------------------------------------------------------------------
__global__ void embed_gather_k(const int* __restrict__ src,
                               const float* __restrict__ table,
                               float* __restrict__ emb)
{
    int t = blockIdx.x;
    int v = src[t];
    for (int k = threadIdx.x; k < FEAT_; k += 256)
        emb[t * FEAT_ + k] = table[v * FEAT_ + k];
}

// ---------------------------------------------------------------------------
// pb[b,i,j] = sum_f pba[f]*cos((frac[b,j]-frac[b,i])*10 * pbW[f] + pbb[f])
// ---------------------------------------------------------------------------
__global__ __launch_bounds__(256)
void pb_k(const float* __restrict__ frac, const float* __restrict__ pbW,
          const float* __restrict__ pbb, const float* __restrict__ pba,
          float* __restrict__ pb)
{
    int idx = blockIdx.x * 256 + threadIdx.x;
    int b = idx >> 14;
    int i = (idx >> 7) & 127;
    int j = idx & 127;
    float diff = (frac[b * T_ + j] - frac[b * T_ + i]) * 10.0f;
    float s = 0.f;
#pragma unroll
    for (int f = 0; f < NF_; ++f)
        s = fmaf(cosf(fmaf(diff, pbW[f], pbb[f])), pba[f], s);
    pb[idx] = s;
}

// ---------------------------------------------------------------------------
// kv[b,c] = sum_t K[b,t,c]*V[b,t,c]
// ---------------------------------------------------------------------------
__global__ __launch_bounds__(256)
void kv_k(const float* __restrict__ K, const float* __restrict__ V,
          float* __restrict__ kv)
{
    int idx = blockIdx.x * 256 + threadIdx.x;   // 64 blocks -> B*D
    int b = idx >> 9, c = idx & 511;
    const float* Kp = K + (long)b * T_ * D_ + c;
    const float* Vp = V + (long)b * T_ * D_ + c;
    float s = 0.f;
    for (int t = 0; t < T_; ++t) s = fmaf(Kp[t * D_], Vp[t * D_], s);
    kv[idx] = s;
}

// ---------------------------------------------------------------------------
// LayerNorm(x + add) -> out       one wave per row of 512
// ---------------------------------------------------------------------------
__global__ __launch_bounds__(256)
void ln_res_k(const float* __restrict__ x, const float* __restrict__ add,
              const float* __restrict__ g, const float* __restrict__ b,
              float* __restrict__ out)
{
    int wave = threadIdx.x >> 6, lane = threadIdx.x & 63;
    int row = blockIdx.x * 4 + wave;
    const float* xr = x   + (long)row * D_ + lane * 8;
    const float* ar = add + (long)row * D_ + lane * 8;
    float v[8]; float s = 0.f;
#pragma unroll
    for (int j = 0; j < 8; ++j) { v[j] = xr[j] + ar[j]; s += v[j]; }
#pragma unroll
    for (int off = 32; off > 0; off >>= 1) s += __shfl_xor(s, off, 64);
    float mean = s * (1.f / D_);
    float q = 0.f;
#pragma unroll
    for (int j = 0; j < 8; ++j) { float d = v[j] - mean; q += d * d; }
#pragma unroll
    for (int off = 32; off > 0; off >>= 1) q += __shfl_xor(q, off, 64);
    float inv = rsqrtf(q * (1.f / D_) + 1e-5f);
    float* orow = out + (long)row * D_ + lane * 8;
#pragma unroll
    for (int j = 0; j < 8; ++j) {
        int c = lane * 8 + j;
        orow[j] = (v[j] - mean) * inv * g[c] + b[c];
    }
}

// ---------------------------------------------------------------------------
// LayerNorm(x + w0*eo[row0] + w1*eo[row1]) -> out   (MoE combine + LN2)
// ---------------------------------------------------------------------------
__global__ __launch_bounds__(256)
void ln_moe_k(const float* __restrict__ x, const float* __restrict__ eo,
              const int* __restrict__ tok_slot, const float* __restrict__ tok_w,
              const int* __restrict__ offsets,
              const float* __restrict__ g, const float* __restrict__ b,
              float* __restrict__ out)
{
    int wave = threadIdx.x >> 6, lane = threadIdx.x & 63;
    int row = blockIdx.x * 4 + wave;
    int  c0 = tok_slot[row * 2], c1 = tok_slot[row * 2 + 1];
    float w0 = tok_w[row * 2],  w1 = tok_w[row * 2 + 1];
    long r0 = offsets[c0 >> 12] + (c0 & 4095);
    long r1 = offsets[c1 >> 12] + (c1 & 4095);
    const float* xr = x  + (long)row * D_ + lane * 8;
    const float* e0 = eo + r0 * D_ + lane * 8;
    const float* e1 = eo + r1 * D_ + lane * 8;
    float v[8]; float s = 0.f;
#pragma unroll
    for (int j = 0; j < 8; ++j) {
        v[j] = xr[j] + w0 * e0[j] + w1 * e1[j];
        s += v[j];
    }
#pragma unroll
    for (int off = 32; off > 0; off >>= 1) s += __shfl_xor(s, off, 64);
    float mean = s * (1.f / D_);
    float q = 0.f;
#pragma unroll
    for (int j = 0; j < 8; ++j) { float d = v[j] - mean; q += d * d; }
#pragma unroll
    for (int off = 32; off > 0; off >>= 1) q += __shfl_xor(q, off, 64);
    float inv = rsqrtf(q * (1.f / D_) + 1e-5f);
    float* orow = out + (long)row * D_ + lane * 8;
#pragma unroll
    for (int j = 0; j < 8; ++j) {
        int c = lane * 8 + j;
        orow[j] = (v[j] - mean) * inv * g[c] + b[c];
    }
}

// ---------------------------------------------------------------------------
// Gate: softmax(x @ gW + gb) -> top2 -> routing lists. One wave per token.
// ---------------------------------------------------------------------------
__global__ __launch_bounds__(256)
void gate_k(const float* __restrict__ x, const float* __restrict__ gW,
            const float* __restrict__ gb, int* __restrict__ counts,
            int* __restrict__ tok_list, int* __restrict__ tok_slot,
            float* __restrict__ tok_w)
{
    int wave = threadIdx.x >> 6, lane = threadIdx.x & 63;
    int t = blockIdx.x * 4 + wave;
    float acc[8];
#pragma unroll
    for (int e = 0; e < 8; ++e) acc[e] = 0.f;
    const float* xr = x + (long)t * D_;
#pragma unroll
    for (int j = 0; j < 8; ++j) {
        int d = lane * 8 + j;
        float xv = xr[d];
        const float* w = gW + d * 8;
#pragma unroll
        for (int e = 0; e < 8; ++e) acc[e] = fmaf(xv, w[e], acc[e]);
    }
#pragma unroll
    for (int off = 32; off > 0; off >>= 1)
#pragma unroll
        for (int e = 0; e < 8; ++e) acc[e] += __shfl_xor(acc[e], off, 64);

    if (lane == 0) {
        float m = -1e30f;
#pragma unroll
        for (int e = 0; e < 8; ++e) { acc[e] += gb[e]; m = fmaxf(m, acc[e]); }
        float p[8]; float s = 0.f;
#pragma unroll
        for (int e = 0; e < 8; ++e) { p[e] = expf(acc[e] - m); s += p[e]; }
        float inv = 1.f / s;
        // top-2, ties -> lower index (matches jax.lax.top_k)
        int e1 = 0;
        for (int e = 1; e < 8; ++e) if (p[e] > p[e1]) e1 = e;
        int e2 = -1;
        for (int e = 0; e < 8; ++e) {
            if (e == e1) continue;
            if (e2 < 0 || p[e] > p[e2]) e2 = e;
        }
        int s1 = atomicAdd(&counts[e1], 1);
        tok_list[e1 * BT_ + s1] = t;
        tok_slot[t * 2]     = (e1 << 12) | s1;
        tok_w[t * 2]        = p[e1] * inv;
        int s2 = atomicAdd(&counts[e2], 1);
        tok_list[e2 * BT_ + s2] = t;
        tok_slot[t * 2 + 1] = (e2 << 12) | s2;
        tok_w[t * 2 + 1]    = p[e2] * inv;
    }
}

__global__ void zero_counts_k(int* __restrict__ counts)
{
    if (threadIdx.x < E_) counts[threadIdx.x] = 0;
}

__global__ void scan_k(const int* __restrict__ counts, int* __restrict__ offsets)
{
    if (threadIdx.x == 0) {
        int s = 0;
        for (int e = 0; e < E_; ++e) { offsets[e] = s; s += counts[e]; }
    }
}

// ---------------------------------------------------------------------------
extern "C" void kernel_launch(void* const* d_in, const int* in_sizes, int n_in,
                              void* d_out, int out_size, void* d_ws, size_t ws_size,
                              hipStream_t stream)
{
    const int*   src   = (const int*)  d_in[0];
    const float* frac  = (const float*)d_in[1];
    const float* table = (const float*)d_in[2];
    const float* W_m2v = (const float*)d_in[3];
    const float* b_m2v = (const float*)d_in[4];
    const float* pbW   = (const float*)d_in[5];
    const float* pbb   = (const float*)d_in[6];
    const float* pba   = (const float*)d_in[7];
    const float* Wk    = (const float*)d_in[8];
    const float* bk    = (const float*)d_in[9];
    const float* Wv    = (const float*)d_in[10];
    const float* bv    = (const float*)d_in[11];
    const float* Wo    = (const float*)d_in[12];
    const float* bo    = (const float*)d_in[13];
    const float* ln1g  = (const float*)d_in[14];
    const float* ln1b  = (const float*)d_in[15];
    const float* ln2g  = (const float*)d_in[16];
    const float* ln2b  = (const float*)d_in[17];
    const float* gW    = (const float*)d_in[18];
    const float* gb    = (const float*)d_in[19];
    const float* eW1   = (const float*)d_in[20];
    const float* eb1   = (const float*)d_in[21];
    const float* eW2   = (const float*)d_in[22];
    const float* eb2   = (const float*)d_in[23];

    float* ws  = (float*)d_ws;
    float* emb = ws;  ws += BT_ * FEAT_;          // 819200
    float* x   = ws;  ws += (long)BT_ * D_;       // 2M
    float* pb  = ws;  ws += (long)B_ * T_ * T_;   // 512K
    float* Kb  = ws;  ws += (long)BT_ * D_;
    float* Vb  = ws;  ws += (long)BT_ * D_;
    float* kv  = ws;  ws += B_ * D_;
    float* wv  = ws;  ws += (long)BT_ * D_;
    float* tmp = ws;  ws += (long)BT_ * D_;
    float* h   = ws;  ws += (long)2 * BT_ * FF_;  // 16.8M floats
    float* eo  = ws;  ws += (long)2 * BT_ * D_;   // 4.2M floats
    float* tokw = ws; ws += 2 * BT_;
    int* counts  = (int*)ws;
    int* offsets = counts + 8;
    int* toklist = offsets + 8;
    int* tokslot = toklist + E_ * BT_;

    // ---- embedder ----
    embed_gather_k<<<BT_, 256, 0, stream>>>(src, table, emb);
    gemm_k<0><<<dim3(8, 64, 1), 256, 0, stream>>>(
        emb, W_m2v, b_m2v, x, FEAT_, FEAT_, D_, D_,
        0, 0, 0, 0, nullptr, nullptr, nullptr);

    // ---- fourier positional bias ----
    pb_k<<<(B_ * T_ * T_) / 256, 256, 0, stream>>>(frac, pbW, pbb, pba, pb);

    for (int i = 0; i < NL_; ++i) {
        const float* Wki = Wk + (long)i * D_ * D_;
        const float* Wvi = Wv + (long)i * D_ * D_;
        const float* Woi = Wo + (long)i * D_ * D_;

        // K, V projections
        gemm_k<0><<<dim3(8, 64, 1), 256, 0, stream>>>(
            x, Wki, bk + i * D_, Kb, D_, D_, D_, D_,
            0, 0, 0, 0, nullptr, nullptr, nullptr);
        gemm_k<0><<<dim3(8, 64, 1), 256, 0, stream>>>(
            x, Wvi, bv + i * D_, Vb, D_, D_, D_, D_,
            0, 0, 0, 0, nullptr, nullptr, nullptr);

        // kv[b,c] reduction
        kv_k<<<(B_ * D_) / 256, 256, 0, stream>>>(Kb, Vb, kv);

        // wv[b] = pb[b] @ V[b] + kv[b]   (batched over b, bias = kv)
        gemm_k<0><<<dim3(8, 2, B_), 256, 0, stream>>>(
            pb, Vb, kv, wv, T_, T_, D_, D_,
            (long)T_ * T_, (long)T_ * D_, (long)T_ * D_, D_,
            nullptr, nullptr, nullptr);

        // attention output projection
        gemm_k<0><<<dim3(8, 64, 1), 256, 0, stream>>>(
            wv, Woi, bo + i * D_, tmp, D_, D_, D_, D_,
            0, 0, 0, 0, nullptr, nullptr, nullptr);

        // x = LN1(x + tmp)
        ln_res_k<<<BT_ / 4, 256, 0, stream>>>(x, tmp, ln1g + i * D_, ln1b + i * D_, x);

        // gating + routing
        zero_counts_k<<<1, 64, 0, stream>>>(counts);
        gate_k<<<BT_ / 4, 256, 0, stream>>>(x, gW + (long)i * D_ * E_, gb + i * E_,
                                            counts, toklist, tokslot, tokw);
        scan_k<<<1, 1, 0, stream>>>(counts, offsets);

        // MoE expert GEMMs (sparse: only routed rows)
        gemm_k<1><<<dim3(FF_ / 64, BT_ / 64, E_), 256, 0, stream>>>(
            x, eW1 + (long)i * E_ * D_ * FF_, eb1 + (long)i * E_ * FF_, h,
            D_, D_, FF_, FF_,
            0, (long)D_ * FF_, 0, FF_, counts, offsets, toklist);
        gemm_k<2><<<dim3(D_ / 64, BT_ / 64, E_), 256, 0, stream>>>(
            h, eW2 + (long)i * E_ * FF_ * D_, eb2 + (long)i * E_ * D_, eo,
            FF_, FF_, D_, D_,
            0, (long)FF_ * D_, 0, D_, counts, offsets, toklist);

        // x = LN2(x + w0*eo0 + w1*eo1); last layer writes d_out
        float* dst = (i == NL_ - 1) ? (float*)d_out : x;
        ln_moe_k<<<BT_ / 4, 256, 0, stream>>>(x, eo, tokslot, tokw, offsets,
                                              ln2g + i * D_, ln2b + i * D_, dst);
    }
}